// Round 1
// baseline (778.317 us; speedup 1.0000x reference)
//
#include <hip/hip_runtime.h>
#include <math.h>

#define HWSZ 4096

__device__ __forceinline__ float sigmoid_f(float x){ return 1.0f/(1.0f + __expf(-x)); }
__device__ __forceinline__ float silu_f(float x){ return x * sigmoid_f(x); }
__device__ __forceinline__ float softplus_f(float x){ return fmaxf(x,0.0f) + __logf(1.0f + __expf(-fabsf(x))); }

// Kernel 1: per-wave sequence processing.
// grid 1024 blocks x 256 threads. Block handles 32 consecutive sequences
// (same b, 32 consecutive hw); wave w handles seqs base + k*4 + w, k=0..7.
// lane = d_inner channel (64 lanes = D_INNER).
__global__ __launch_bounds__(256, 2) void spe_main(
    const float* __restrict__ x,
    const float* __restrict__ in_proj_w,
    const float* __restrict__ conv_w_f, const float* __restrict__ conv_b_f,
    const float* __restrict__ conv_w_b, const float* __restrict__ conv_b_b,
    const float* __restrict__ x_proj_w_f, const float* __restrict__ x_proj_w_b,
    const float* __restrict__ dt_proj_w_f, const float* __restrict__ dt_proj_b_f,
    const float* __restrict__ dt_proj_w_b, const float* __restrict__ dt_proj_b_b,
    const float* __restrict__ A_log_f, const float* __restrict__ A_log_b,
    const float* __restrict__ D_f, const float* __restrict__ D_b,
    const float* __restrict__ out_proj_w,
    float* __restrict__ out, float* __restrict__ sums)
{
    // x_proj weights transposed: [d][bj] with bj = branch*34 + j (row len 68)
    __shared__ __align__(16) float xw_T[64*68];
    __shared__ __align__(16) float xf_lds[4][256];      // [wave][t*32+m]
    __shared__ __align__(16) float uc_lds[4][2][8][64]; // [wave][branch][t][d]
    __shared__ __align__(16) float dbl_lds[4][576];     // [wave][(t*2+br)*36 + slot]; dt:0-1 B:4-19 C:20-35
    __shared__ __align__(16) float y_lds[4][8][64];     // [wave][t][d]

    const int tid = threadIdx.x;
    const int wid = tid >> 6;
    const int l   = tid & 63;

    // stage x_proj weights (one-time)
    for (int idx = tid; idx < 64*68; idx += 256){
        int d = idx / 68, bj = idx - d*68;
        const float* w = (bj < 34) ? x_proj_w_f : x_proj_w_b;
        int j = (bj < 34) ? bj : bj - 34;
        xw_T[idx] = w[j*64 + d];
    }

    // ---- per-lane weights in registers ----
    float w_u[32], w_z[32], w_o[64], A_f[16], A_b[16];
    {
        const float4* pu = (const float4*)(in_proj_w + l*32);
        const float4* pz = (const float4*)(in_proj_w + (64+l)*32);
        #pragma unroll
        for (int m4=0;m4<8;m4++){
            float4 a = pu[m4];
            w_u[m4*4+0]=a.x; w_u[m4*4+1]=a.y; w_u[m4*4+2]=a.z; w_u[m4*4+3]=a.w;
            float4 c = pz[m4];
            w_z[m4*4+0]=c.x; w_z[m4*4+1]=c.y; w_z[m4*4+2]=c.z; w_z[m4*4+3]=c.w;
        }
        const float4* po = (const float4*)(out_proj_w + (l&31)*64);
        #pragma unroll
        for (int m4=0;m4<16;m4++){
            float4 a = po[m4];
            w_o[m4*4+0]=a.x; w_o[m4*4+1]=a.y; w_o[m4*4+2]=a.z; w_o[m4*4+3]=a.w;
        }
        const float4* pa = (const float4*)(A_log_f + l*16);
        const float4* pb = (const float4*)(A_log_b + l*16);
        #pragma unroll
        for (int s4=0;s4<4;s4++){
            float4 a = pa[s4];
            A_f[s4*4+0]=-__expf(a.x); A_f[s4*4+1]=-__expf(a.y);
            A_f[s4*4+2]=-__expf(a.z); A_f[s4*4+3]=-__expf(a.w);
            float4 c = pb[s4];
            A_b[s4*4+0]=-__expf(c.x); A_b[s4*4+1]=-__expf(c.y);
            A_b[s4*4+2]=-__expf(c.z); A_b[s4*4+3]=-__expf(c.w);
        }
    }
    const float cw0f=conv_w_f[l*2], cw1f=conv_w_f[l*2+1], cbf=conv_b_f[l];
    const float cw0b=conv_w_b[l*2], cw1b=conv_w_b[l*2+1], cbb=conv_b_b[l];
    const float dtw0f=dt_proj_w_f[l*2], dtw1f=dt_proj_w_f[l*2+1], dtbf=dt_proj_b_f[l];
    const float dtw0b=dt_proj_w_b[l*2], dtw1b=dt_proj_w_b[l*2+1], dtbb=dt_proj_b_b[l];
    const float Dfv=D_f[l], Dbv=D_b[l];

    const int b = blockIdx.x >> 7;             // 128 blocks per batch
    const int hwbase = (blockIdx.x & 127) * 32;
    const float* xb = x + b*(256*HWSZ);
    float* outb0 = out + b*(256*HWSZ);

    float gs[4] = {0,0,0,0};  // group sums (group == r, since c = r*64 + lane)
    float gq[4] = {0,0,0,0};

    __syncthreads();

    #pragma unroll 1
    for (int k=0;k<8;k++){
        const int hw = hwbase + k*4 + wid;

        // stage this sequence's tokens: xf[t*32+m] = x[b, c=t*32+m, hw]
        #pragma unroll
        for (int r=0;r<4;r++)
            xf_lds[wid][r*64 + l] = xb[(r*64 + l)*HWSZ + hw];
        __syncthreads();

        // ---- in_proj: u[t] = xf[t]·w_u(lane), z -> silu(z) ----
        float u[8], siluz[8];
        #pragma unroll
        for (int t=0;t<8;t++){
            const float4* xf4 = (const float4*)&xf_lds[wid][t*32];
            float au0=0,au1=0,au2=0,au3=0, az0=0,az1=0,az2=0,az3=0;
            #pragma unroll
            for (int m4=0;m4<8;m4++){
                float4 xv = xf4[m4];
                au0 = fmaf(xv.x, w_u[m4*4+0], au0);
                au1 = fmaf(xv.y, w_u[m4*4+1], au1);
                au2 = fmaf(xv.z, w_u[m4*4+2], au2);
                au3 = fmaf(xv.w, w_u[m4*4+3], au3);
                az0 = fmaf(xv.x, w_z[m4*4+0], az0);
                az1 = fmaf(xv.y, w_z[m4*4+1], az1);
                az2 = fmaf(xv.z, w_z[m4*4+2], az2);
                az3 = fmaf(xv.w, w_z[m4*4+3], az3);
            }
            u[t] = (au0+au1)+(au2+au3);
            siluz[t] = silu_f((az0+az1)+(az2+az3));
        }

        // ---- causal conv (fwd & flipped) + silu ----
        float ucf[8], ucb[8];
        #pragma unroll
        for (int t=0;t<8;t++){
            float prev = (t>0)? u[t-1] : 0.0f;
            ucf[t] = silu_f(fmaf(prev, cw0f, fmaf(u[t], cw1f, cbf)));
        }
        #pragma unroll
        for (int t=0;t<8;t++){            // backward branch operates on flip(u)
            float prev = (t>0)? u[8-t] : 0.0f;
            ucb[t] = silu_f(fmaf(prev, cw0b, fmaf(u[7-t], cw1b, cbb)));
        }
        #pragma unroll
        for (int t=0;t<8;t++){ uc_lds[wid][0][t][l]=ucf[t]; uc_lds[wid][1][t][l]=ucb[t]; }
        __syncthreads();

        // ---- x_proj: 8 tokens x 2 branches x 34 outputs = 544 dot products over d=64 ----
        for (int k2=0;k2<9;k2++){
            int o = k2*64 + l;
            int act = (o < 544) ? 1 : 0;
            int oc = act ? o : 0;
            int t = oc / 68;
            int r68 = oc - t*68;
            int br = (r68 >= 34) ? 1 : 0;
            int j = r68 - br*34;
            const float4* ucp = (const float4*)&uc_lds[wid][br][t][0];
            const float* wp = &xw_T[br*34 + j];
            float a0=0,a1=0,a2=0,a3=0;
            #pragma unroll
            for (int d4=0; d4<16; d4++){
                float4 uv = ucp[d4];
                a0 = fmaf(uv.x, wp[(d4*4+0)*68], a0);
                a1 = fmaf(uv.y, wp[(d4*4+1)*68], a1);
                a2 = fmaf(uv.z, wp[(d4*4+2)*68], a2);
                a3 = fmaf(uv.w, wp[(d4*4+3)*68], a3);
            }
            if (act){
                int jm = j + ((j>=2)?2:0);     // dt->0..1, B->4..19, C->20..35
                dbl_lds[wid][(t*2+br)*36 + jm] = (a0+a1)+(a2+a3);
            }
        }
        __syncthreads();

        // ---- selective scans (lane d keeps h[16]) ----
        float h[16], yf[8];
        #pragma unroll
        for (int s=0;s<16;s++) h[s]=0.0f;
        #pragma unroll
        for (int t=0;t<8;t++){
            const float* sl = &dbl_lds[wid][(t*2+0)*36];
            float delta = softplus_f(fmaf(sl[0], dtw0f, fmaf(sl[1], dtw1f, dtbf)));
            float du = delta * ucf[t];
            const float4* B4 = (const float4*)(sl+4);
            const float4* C4 = (const float4*)(sl+20);
            float y=0.0f;
            #pragma unroll
            for (int s4=0;s4<4;s4++){
                float4 Bv=B4[s4], Cv=C4[s4];
                float e0=__expf(delta*A_f[s4*4+0]);
                h[s4*4+0]=fmaf(e0,h[s4*4+0],du*Bv.x); y=fmaf(h[s4*4+0],Cv.x,y);
                float e1=__expf(delta*A_f[s4*4+1]);
                h[s4*4+1]=fmaf(e1,h[s4*4+1],du*Bv.y); y=fmaf(h[s4*4+1],Cv.y,y);
                float e2=__expf(delta*A_f[s4*4+2]);
                h[s4*4+2]=fmaf(e2,h[s4*4+2],du*Bv.z); y=fmaf(h[s4*4+2],Cv.z,y);
                float e3=__expf(delta*A_f[s4*4+3]);
                h[s4*4+3]=fmaf(e3,h[s4*4+3],du*Bv.w); y=fmaf(h[s4*4+3],Cv.w,y);
            }
            yf[t] = fmaf(Dfv, ucf[t], y);
        }
        #pragma unroll
        for (int s=0;s<16;s++) h[s]=0.0f;
        #pragma unroll
        for (int tau=0;tau<8;tau++){
            const float* sl = &dbl_lds[wid][(tau*2+1)*36];
            float delta = softplus_f(fmaf(sl[0], dtw0b, fmaf(sl[1], dtw1b, dtbb)));
            float du = delta * ucb[tau];
            const float4* B4 = (const float4*)(sl+4);
            const float4* C4 = (const float4*)(sl+20);
            float y=0.0f;
            #pragma unroll
            for (int s4=0;s4<4;s4++){
                float4 Bv=B4[s4], Cv=C4[s4];
                float e0=__expf(delta*A_b[s4*4+0]);
                h[s4*4+0]=fmaf(e0,h[s4*4+0],du*Bv.x); y=fmaf(h[s4*4+0],Cv.x,y);
                float e1=__expf(delta*A_b[s4*4+1]);
                h[s4*4+1]=fmaf(e1,h[s4*4+1],du*Bv.y); y=fmaf(h[s4*4+1],Cv.y,y);
                float e2=__expf(delta*A_b[s4*4+2]);
                h[s4*4+2]=fmaf(e2,h[s4*4+2],du*Bv.z); y=fmaf(h[s4*4+2],Cv.z,y);
                float e3=__expf(delta*A_b[s4*4+3]);
                h[s4*4+3]=fmaf(e3,h[s4*4+3],du*Bv.w); y=fmaf(h[s4*4+3],Cv.w,y);
            }
            float ytb = fmaf(Dbv, ucb[tau], y);
            int t = 7-tau;                 // un-flip
            y_lds[wid][t][l] = (yf[t] + ytb) * siluz[t];
        }
        __syncthreads();

        // ---- out_proj (lane l -> channel c = r*64 + l, row m = l&31) + GN partials ----
        {
            const int half = l >> 5;
            float* outp = outb0 + hw;
            #pragma unroll
            for (int r=0;r<4;r++){
                int t = 2*r + half;
                const float4* yp = (const float4*)&y_lds[wid][t][0];
                float a0=0,a1=0,a2=0,a3=0;
                #pragma unroll
                for (int d4=0; d4<16; d4++){
                    float4 yv = yp[d4];
                    a0=fmaf(yv.x, w_o[d4*4+0], a0);
                    a1=fmaf(yv.y, w_o[d4*4+1], a1);
                    a2=fmaf(yv.z, w_o[d4*4+2], a2);
                    a3=fmaf(yv.w, w_o[d4*4+3], a3);
                }
                float val = (a0+a1)+(a2+a3);
                outp[(r*64 + l)*HWSZ] = val;   // pre-GN, (B,C,H,W) layout
                gs[r] += val;
                gq[r] = fmaf(val, val, gq[r]);
            }
        }
        __syncthreads();
    }

    // ---- wave-reduce GN partials, one atomic pair per (wave, group) ----
    #pragma unroll
    for (int r=0;r<4;r++){
        float s = gs[r], q = gq[r];
        #pragma unroll
        for (int off=32; off>=1; off>>=1){
            s += __shfl_xor(s, off, 64);
            q += __shfl_xor(q, off, 64);
        }
        if (l==0){
            atomicAdd(&sums[b*8 + r*2],     s);
            atomicAdd(&sums[b*8 + r*2 + 1], q);
        }
    }
}

// Kernel 2: in-place GroupNorm apply + SiLU + residual. 4 floats/thread.
__global__ void spe_gn(float* __restrict__ out, const float* __restrict__ x,
                       const float* __restrict__ sums,
                       const float* __restrict__ gn_w, const float* __restrict__ gn_b)
{
    int i = (blockIdx.x*256 + threadIdx.x)*4;
    int c = (i >> 12) & 255;
    int b = i >> 20;
    int g = c >> 6;
    float s = sums[b*8 + g*2];
    float q = sums[b*8 + g*2 + 1];
    const float invN = 1.0f/262144.0f;   // 64 channels * 4096 hw
    float mean = s*invN;
    float var  = fmaf(-mean, mean, q*invN);
    float rstd = rsqrtf(var + 1e-5f);
    float wv = gn_w[c]*rstd;
    float bv = fmaf(-mean, wv, gn_b[c]);
    float4 o  = *(const float4*)(out + i);
    float4 xv = *(const float4*)(x + i);
    float v0 = fmaf(o.x, wv, bv);
    float v1 = fmaf(o.y, wv, bv);
    float v2 = fmaf(o.z, wv, bv);
    float v3 = fmaf(o.w, wv, bv);
    float4 res;
    res.x = xv.x + v0*sigmoid_f(v0);
    res.y = xv.y + v1*sigmoid_f(v1);
    res.z = xv.z + v2*sigmoid_f(v2);
    res.w = xv.w + v3*sigmoid_f(v3);
    *(float4*)(out + i) = res;
}

extern "C" void kernel_launch(void* const* d_in, const int* in_sizes, int n_in,
                              void* d_out, int out_size, void* d_ws, size_t ws_size,
                              hipStream_t stream) {
    (void)in_sizes; (void)n_in; (void)out_size; (void)ws_size;
    const float* x          = (const float*)d_in[0];
    const float* in_proj_w  = (const float*)d_in[1];
    const float* conv_w_f   = (const float*)d_in[2];
    const float* conv_b_f   = (const float*)d_in[3];
    const float* conv_w_b   = (const float*)d_in[4];
    const float* conv_b_b   = (const float*)d_in[5];
    const float* x_proj_w_f = (const float*)d_in[6];
    const float* x_proj_w_b = (const float*)d_in[7];
    const float* dt_proj_w_f= (const float*)d_in[8];
    const float* dt_proj_b_f= (const float*)d_in[9];
    const float* dt_proj_w_b= (const float*)d_in[10];
    const float* dt_proj_b_b= (const float*)d_in[11];
    const float* A_log_f    = (const float*)d_in[12];
    const float* A_log_b    = (const float*)d_in[13];
    const float* D_f        = (const float*)d_in[14];
    const float* D_b        = (const float*)d_in[15];
    const float* out_proj_w = (const float*)d_in[16];
    const float* gn_w       = (const float*)d_in[17];
    const float* gn_b       = (const float*)d_in[18];
    float* out  = (float*)d_out;
    float* sums = (float*)d_ws;

    hipMemsetAsync(d_ws, 0, 64*sizeof(float), stream);
    spe_main<<<1024, 256, 0, stream>>>(x, in_proj_w,
        conv_w_f, conv_b_f, conv_w_b, conv_b_b,
        x_proj_w_f, x_proj_w_b,
        dt_proj_w_f, dt_proj_b_f, dt_proj_w_b, dt_proj_b_b,
        A_log_f, A_log_b, D_f, D_b, out_proj_w, out, sums);
    spe_gn<<<8192, 256, 0, stream>>>(out, x, sums, gn_w, gn_b);
}